// Round 6
// baseline (764.997 us; speedup 1.0000x reference)
//
#include <hip/hip_runtime.h>
#include <hip/hip_bf16.h>
#include <math.h>
#include <stdint.h>

#define LSEQ 1024
#define DMODEL 768
#define DINNER 1536
#define DSTATE 16
#define DRANK 48
#define KCONV 4
#define NLAYER 2
#define DBC 80  // DRANK + 2*DSTATE

typedef unsigned short u16;
typedef __attribute__((ext_vector_type(8))) __bf16 bf16x8;
typedef __attribute__((ext_vector_type(4))) float f32x4;
typedef __attribute__((ext_vector_type(4))) unsigned short us4;

__device__ __forceinline__ u16 f2bf(float f) {
  union { float f; unsigned u; } v; v.f = f;
  unsigned r = v.u + 0x7fffu + ((v.u >> 16) & 1u);  // RNE
  return (u16)(r >> 16);
}

// CK-style addrspace casts for global_load_lds (direct HBM->LDS DMA, 16B/lane)
__device__ __forceinline__ void gload16(const void* g, void* l) {
  auto gp = reinterpret_cast<const __attribute__((address_space(1))) uint32_t*>(
      reinterpret_cast<uintptr_t>(g));
  auto lp = reinterpret_cast<__attribute__((address_space(3))) uint32_t*>(
      reinterpret_cast<uintptr_t>(l));
  __builtin_amdgcn_global_load_lds(gp, lp, 16, 0, 0);
}

// ---------------- fp32 -> bf16 flat convert ----------------
__global__ __launch_bounds__(256) void cvt_k(const float* __restrict__ in,
                                             u16* __restrict__ out, int n4) {
  int i = blockIdx.x * 256 + threadIdx.x;
  if (i >= n4) return;
  float4 v = ((const float4*)in)[i];
  us4 o; o[0] = f2bf(v.x); o[1] = f2bf(v.y); o[2] = f2bf(v.z); o[3] = f2bf(v.w);
  ((us4*)out)[i] = o;
}

// ---------------- fp32 -> bf16 transpose-convert (out[c][r] = in[r][c]) -------
__global__ __launch_bounds__(256) void transcvt_k(const float* __restrict__ in,
                                                  u16* __restrict__ out,
                                                  int R, int C) {
  __shared__ float t[32][33];
  int c0 = blockIdx.x * 32, r0 = blockIdx.y * 32;
  int tx = threadIdx.x & 31, ty = threadIdx.x >> 5;
  for (int i = ty; i < 32; i += 8) t[i][tx] = in[(size_t)(r0 + i) * C + c0 + tx];
  __syncthreads();
  for (int i = ty; i < 32; i += 8)
    out[(size_t)(c0 + i) * R + r0 + tx] = f2bf(t[tx][i]);
}

// ---------------- bf16 -> bf16 transpose ----------------
__global__ __launch_bounds__(256) void transpose16_k(const u16* __restrict__ in,
                                                     u16* __restrict__ out,
                                                     int R, int C) {
  __shared__ u16 t[32][34];
  int c0 = blockIdx.x * 32, r0 = blockIdx.y * 32;
  int tx = threadIdx.x & 31, ty = threadIdx.x >> 5;
  for (int i = ty; i < 32; i += 8) t[i][tx] = in[(size_t)(r0 + i) * C + c0 + tx];
  __syncthreads();
  for (int i = ty; i < 32; i += 8)
    out[(size_t)(c0 + i) * R + r0 + tx] = t[tx][i];
}

// ---------------- rmsnorm (bf16 out) ----------------
__global__ __launch_bounds__(256) void rmsnorm_k(const float* __restrict__ x,
                                                 const float* __restrict__ w,
                                                 u16* __restrict__ xn) {
  int row = blockIdx.x;
  int tid = threadIdx.x;
  const float* xr = x + (size_t)row * DMODEL;
  float ss = 0.f;
  for (int j = tid; j < DMODEL; j += 256) { float v = xr[j]; ss += v * v; }
  __shared__ float red[256];
  red[tid] = ss; __syncthreads();
  for (int s = 128; s > 0; s >>= 1) { if (tid < s) red[tid] += red[tid + s]; __syncthreads(); }
  float scale = rsqrtf(red[0] / (float)DMODEL + 1e-5f);
  u16* outr = xn + (size_t)row * DMODEL;
  for (int j = tid; j < DMODEL; j += 256) outr[j] = f2bf(xr[j] * scale * w[j]);
}

// ---------------- MFMA bf16 GEMM, depth-3 pipelined (T3/T4 minimum form) -----
// C[m,n] = sum_k A[m,k]*B[n,k]; A [M,K] bf16, B [N,K] bf16 (NT).
// 128x128 tile, BK=32, 4 waves each 64x64 (4x4 frags of 16x16x32).
// 4 LDS buffers; counted vmcnt (8/4/0) + raw s_barrier -> loads in flight
// across barriers. LDS layout [k-slot][row] (bank-minimal frag reads);
// gload dest stays linear, global source pre-permuted per lane (rule #21).
// EPI bit0: +bias[n]; bit2: +resid fp32; bit3: bf16 output.
template<int EPI>
__global__ __launch_bounds__(256) void mgemm_k(
    const u16* __restrict__ A, int lda,
    const u16* __restrict__ B, int ldb,
    void* __restrict__ Cv, int ldc, int K,
    const float* __restrict__ bias,
    const float* __restrict__ resid, int ldr)
{
  // per buffer: slot s (k = s*8..s*8+7) x 128 rows x 8 u16 = 4096 u16 = 8 KB
  __shared__ u16 As[4][4096];
  __shared__ u16 Bs[4][4096];
  const int tid = threadIdx.x;
  const int lane = tid & 63;
  const int wid = tid >> 6;
  const int bm = blockIdx.y * 128;
  const int bn = blockIdx.x * 128;
  const int wm = (wid >> 1) * 64;
  const int wn = (wid & 1) * 64;

  // staging: wave wid covers slots {wid>>1, 2+(wid>>1)} over row-half (wid&1).
  // lane L lands at dest base + L*16B -> row = (wid&1)*64 + L of that slot.
  const int srow = (wid & 1) * 64 + lane;
  const int s0 = wid >> 1;
  const u16* Ag0 = A + (size_t)(bm + srow) * lda + s0 * 8;
  const u16* Ag1 = A + (size_t)(bm + srow) * lda + (2 + s0) * 8;
  const u16* Bg0 = B + (size_t)(bn + srow) * ldb + s0 * 8;
  const u16* Bg1 = B + (size_t)(bn + srow) * ldb + (2 + s0) * 8;
  const int da0 = s0 * 1024 + (wid & 1) * 512;        // u16 offset, wave-uniform
  const int da1 = (2 + s0) * 1024 + (wid & 1) * 512;

  f32x4 acc[4][4];
#pragma unroll
  for (int i = 0; i < 4; i++)
#pragma unroll
    for (int j = 0; j < 4; j++) acc[i][j] = (f32x4){0.f, 0.f, 0.f, 0.f};

#define STAGE(buf, k0) do { \
    gload16(Ag0 + (k0), &As[buf][da0]); \
    gload16(Ag1 + (k0), &As[buf][da1]); \
    gload16(Bg0 + (k0), &Bs[buf][da0]); \
    gload16(Bg1 + (k0), &Bs[buf][da1]); \
  } while (0)

  const int nk = K >> 5;        // all K here are multiples of 32, nk >= 24
  STAGE(0, 0);
  STAGE(1, 32);
  STAGE(2, 64);

  const int fr = lane & 15;     // fragment row within 16
  const int fs = lane >> 4;     // k-slot 0..3

  for (int t = 0; t < nk; t++) {
    // wait for tile t's 4 loads (per wave); keep up to 2 newer tiles in flight
    if (t + 2 < nk)      asm volatile("s_waitcnt vmcnt(8)" ::: "memory");
    else if (t + 1 < nk) asm volatile("s_waitcnt vmcnt(4)" ::: "memory");
    else                 asm volatile("s_waitcnt vmcnt(0)" ::: "memory");
    __builtin_amdgcn_sched_barrier(0);
    __builtin_amdgcn_s_barrier();   // raw: no vmcnt(0) drain
    __builtin_amdgcn_sched_barrier(0);
    if (t + 3 < nk) STAGE((t + 3) & 3, (t + 3) * 32);  // buffer read at t-1: free

    const int buf = t & 3;
    const u16* ab = &As[buf][fs * 1024 + (wm + fr) * 8];
    const u16* bb = &Bs[buf][fs * 1024 + (wn + fr) * 8];
    bf16x8 af[4], bfv[4];
#pragma unroll
    for (int i = 0; i < 4; i++) af[i]  = *reinterpret_cast<const bf16x8*>(ab + i * 128);
#pragma unroll
    for (int j = 0; j < 4; j++) bfv[j] = *reinterpret_cast<const bf16x8*>(bb + j * 128);
#pragma unroll
    for (int i = 0; i < 4; i++)
#pragma unroll
      for (int j = 0; j < 4; j++)
        acc[i][j] = __builtin_amdgcn_mfma_f32_16x16x32_bf16(af[i], bfv[j], acc[i][j], 0, 0, 0);
  }
#undef STAGE

  const int fq = lane >> 4;
#pragma unroll
  for (int i = 0; i < 4; i++) {
#pragma unroll
    for (int j = 0; j < 4; j++) {
      const int col = bn + wn + j * 16 + fr;
      const int row0 = bm + wm + i * 16 + fq * 4;
      float bv = (EPI & 1) ? bias[col] : 0.f;
#pragma unroll
      for (int r = 0; r < 4; r++) {
        float v = acc[i][j][r] + bv;
        if (EPI & 4) v += resid[(size_t)(row0 + r) * ldr + col];
        if (EPI & 8) ((u16*)Cv)[(size_t)(row0 + r) * ldc + col] = f2bf(v);
        else         ((float*)Cv)[(size_t)(row0 + r) * ldc + col] = v;
      }
    }
  }
}

// ---------------- thin dbc GEMM: partial[ks][1024][80], K-split 16x96 ---------
#define TG_R 16
#define TG_KC 96
#define TG_KS 16

__global__ __launch_bounds__(256) void thin_gemm_k(
    const float* __restrict__ A,   // [1024][1536]
    const float* __restrict__ B,   // [80][1536]
    float* __restrict__ partial)   // [TG_KS][1024][80]
{
  __shared__ float As[TG_R][100];
  __shared__ float Bs[80][100];
  const int tid = threadIdx.x;
  const int m0 = blockIdx.x * TG_R;
  const int ks = blockIdx.y;
  const int k0 = ks * TG_KC;

  for (int i = tid; i < 384; i += 256) {   // A tile: 16 rows x 96 = 384 float4
    int r = i / 24, q = i % 24;
    *(float4*)&As[r][q * 4] = *(const float4*)(A + (size_t)(m0 + r) * DINNER + k0 + q * 4);
  }
  for (int i = tid; i < 1920; i += 256) {  // B tile: 80 x 96 = 1920 float4
    int r = i / 24, q = i % 24;
    *(float4*)&Bs[r][q * 4] = *(const float4*)(B + (size_t)r * DINNER + k0 + q * 4);
  }
  __syncthreads();

  const int r = tid >> 4;
  const int c0 = (tid & 15) * 5;
  float acc[5] = {};
  for (int k = 0; k < TG_KC; k++) {
    float a = As[r][k];
#pragma unroll
    for (int j = 0; j < 5; j++) acc[j] += a * Bs[c0 + j][k];
  }
  float* out = partial + ((size_t)ks * LSEQ + m0 + r) * DBC + c0;
#pragma unroll
  for (int j = 0; j < 5; j++) out[j] = acc[j];
}

__global__ __launch_bounds__(256) void reduce_dbc_k(const float* __restrict__ partial,
                                                    float* __restrict__ out) {
  int i = blockIdx.x * 256 + threadIdx.x;
  float s = 0.f;
#pragma unroll
  for (int ks = 0; ks < TG_KS; ks++) s += partial[(size_t)ks * (LSEQ * DBC) + i];
  out[i] = s;
}

// ---------------- fp32 tiled GEMM (delta: softplus path) ----------
#define BM 64
#define BN 64
#define BK 16

template<int EPI>  // bit0 bias, bit1 softplus
__global__ __launch_bounds__(256) void gemm_k(
    const float* __restrict__ A, int lda,
    const float* __restrict__ B, int ldb,
    float* __restrict__ C, int ldc,
    int M, int N, int K,
    const float* __restrict__ bias)
{
  __shared__ float Asf[BK][BM];
  __shared__ float Bsf[BK][BN + 4];
  const int tid = threadIdx.x;
  const int bm = blockIdx.y * BM;
  const int bn = blockIdx.x * BN;
  const int ar = tid >> 2;
  const int ak = (tid & 3) << 2;
  const int ty = tid >> 4, tx = tid & 15;
  float acc[4][4] = {};

  for (int k0 = 0; k0 < K; k0 += BK) {
    float4 av = *(const float4*)(A + (size_t)(bm + ar) * lda + k0 + ak);
    float4 bv = make_float4(0.f, 0.f, 0.f, 0.f);
    if (bn + ar < N) bv = *(const float4*)(B + (size_t)(bn + ar) * ldb + k0 + ak);
    __syncthreads();
    Asf[ak + 0][ar] = av.x; Asf[ak + 1][ar] = av.y;
    Asf[ak + 2][ar] = av.z; Asf[ak + 3][ar] = av.w;
    Bsf[ak + 0][ar] = bv.x; Bsf[ak + 1][ar] = bv.y;
    Bsf[ak + 2][ar] = bv.z; Bsf[ak + 3][ar] = bv.w;
    __syncthreads();
#pragma unroll
    for (int kk = 0; kk < BK; kk++) {
      float4 a4 = *(const float4*)&Asf[kk][ty * 4];
      float4 b4 = *(const float4*)&Bsf[kk][tx * 4];
      float a[4] = {a4.x, a4.y, a4.z, a4.w};
      float b[4] = {b4.x, b4.y, b4.z, b4.w};
#pragma unroll
      for (int i = 0; i < 4; i++)
#pragma unroll
        for (int j = 0; j < 4; j++)
          acc[i][j] += a[i] * b[j];
    }
  }

#pragma unroll
  for (int i = 0; i < 4; i++) {
    int row = bm + ty * 4 + i;
#pragma unroll
    for (int j = 0; j < 4; j++) {
      int col = bn + tx * 4 + j;
      if (col < N) {
        float v = acc[i][j];
        if (EPI & 1) v += bias[col];
        if (EPI & 2) v = (v > 20.f) ? v : log1pf(__expf(v));
        C[(size_t)row * ldc + col] = v;
      }
    }
  }
}

// ---------------- causal depthwise conv + silu (both directions) -------------
__global__ __launch_bounds__(256) void conv_silu_k(
    const float* __restrict__ xz,
    const float* __restrict__ wf, const float* __restrict__ bf,
    const float* __restrict__ wb, const float* __restrict__ bb,
    float* __restrict__ xf, float* __restrict__ xb)
{
  int idx = blockIdx.x * 256 + threadIdx.x;
  int dir = blockIdx.y;
  if (idx >= LSEQ * DINNER) return;
  int l = idx / DINNER, c = idx % DINNER;
  const float* w = (dir ? wb : wf) + c * KCONV;
  float acc = (dir ? bb : bf)[c];
#pragma unroll
  for (int k = 0; k < KCONV; k++) {
    int ls = l - (KCONV - 1) + k;
    if (ls >= 0) {
      int lsrc = dir ? (LSEQ - 1 - ls) : ls;
      acc += w[k] * xz[(size_t)lsrc * (2 * DINNER) + c];
    }
  }
  float sv = acc / (1.f + __expf(-acc));
  (dir ? xb : xf)[idx] = sv;
}

// ---------------- chunked selective scan: 64 chunks x 4 channels -------------
#define SCH 64
#define SCPB 4
__global__ __launch_bounds__(256) void scan_k(
    const float* __restrict__ xc,
    const float* __restrict__ delta,
    const float* __restrict__ dbc,
    const float* __restrict__ A_log,
    const float* __restrict__ Dvec,
    u16* __restrict__ ycat,
    int col_off)
{
  __shared__ float sP[SCH * SCPB * DSTATE];
  __shared__ float sQ[SCH * SCPB * DSTATE];
  const int tid = threadIdx.x;
  const int c = tid >> 2;
  const int dl = tid & 3;
  const int d = blockIdx.x * SCPB + dl;
  const int CH = LSEQ / SCH;

  float Aa[DSTATE];
#pragma unroll
  for (int s = 0; s < DSTATE; s++) Aa[s] = -__expf(A_log[(size_t)d * DSTATE + s]);

  float aP[DSTATE], q[DSTATE];
#pragma unroll
  for (int s = 0; s < DSTATE; s++) { aP[s] = 1.f; q[s] = 0.f; }
  const int l0 = c * CH;
  for (int i = 0; i < CH; i++) {
    int l = l0 + i;
    float dt = delta[(size_t)l * DINNER + d];
    float dx = dt * xc[(size_t)l * DINNER + d];
    const float* bm = dbc + (size_t)l * DBC + DRANK;
#pragma unroll
    for (int s = 0; s < DSTATE; s++) {
      float a = __expf(dt * Aa[s]);
      q[s] = a * q[s] + dx * bm[s];
      aP[s] *= a;
    }
  }
#pragma unroll
  for (int s = 0; s < DSTATE; s++) {
    sP[(c * SCPB + dl) * DSTATE + s] = aP[s];
    sQ[(c * SCPB + dl) * DSTATE + s] = q[s];
  }
  __syncthreads();

  if (tid < SCPB * DSTATE) {
    const int d2 = tid >> 4, s2 = tid & 15;
    float h = 0.f;
    for (int cc = 0; cc < SCH; cc++) {
      int idx = (cc * SCPB + d2) * DSTATE + s2;
      float a = sP[idx], qq = sQ[idx];
      sP[idx] = h;
      h = a * h + qq;
    }
  }
  __syncthreads();

  float hs[DSTATE];
#pragma unroll
  for (int s = 0; s < DSTATE; s++) hs[s] = sP[(c * SCPB + dl) * DSTATE + s];
  const float Dd = Dvec[d];
  for (int i = 0; i < CH; i++) {
    int l = l0 + i;
    float dt = delta[(size_t)l * DINNER + d];
    float xv = xc[(size_t)l * DINNER + d];
    float dx = dt * xv;
    const float* bm = dbc + (size_t)l * DBC + DRANK;
    const float* cm = bm + DSTATE;
    float y = 0.f;
#pragma unroll
    for (int s = 0; s < DSTATE; s++) {
      float a = __expf(dt * Aa[s]);
      hs[s] = a * hs[s] + dx * bm[s];
      y += hs[s] * cm[s];
    }
    ycat[(size_t)l * (2 * DINNER) + col_off + d] = f2bf(y + Dd * xv);
  }
}

// ---------------- row softmax (fp32 in, bf16 out) ----------------
__global__ __launch_bounds__(256) void softmax_k(const float* __restrict__ S,
                                                 u16* __restrict__ P) {
  int row = blockIdx.x, tid = threadIdx.x;
  __shared__ float buf[LSEQ];
  __shared__ float red[256];
  const float* r = S + (size_t)row * LSEQ;
  float m = -1e30f;
  for (int j = tid; j < LSEQ; j += 256) { float v = r[j]; buf[j] = v; m = fmaxf(m, v); }
  red[tid] = m; __syncthreads();
  for (int s = 128; s > 0; s >>= 1) { if (tid < s) red[tid] = fmaxf(red[tid], red[tid + s]); __syncthreads(); }
  m = red[0];
  __syncthreads();
  float sum = 0.f;
  for (int j = tid; j < LSEQ; j += 256) { float e = __expf(buf[j] - m); buf[j] = e; sum += e; }
  red[tid] = sum; __syncthreads();
  for (int s = 128; s > 0; s >>= 1) { if (tid < s) red[tid] += red[tid + s]; __syncthreads(); }
  float inv = 1.f / red[0];
  u16* pr = P + (size_t)row * LSEQ;
  for (int j = tid; j < LSEQ; j += 256) pr[j] = f2bf(buf[j] * inv);
}

// ---------------- g = y2 * silu(z) (bf16 out) ----------------
__global__ __launch_bounds__(256) void silumul_k(const float* __restrict__ y2,
                                                 const float* __restrict__ xz,
                                                 u16* __restrict__ g) {
  int idx = blockIdx.x * 256 + threadIdx.x;
  if (idx >= LSEQ * DINNER) return;
  int l = idx / DINNER, d = idx % DINNER;
  float z = xz[(size_t)l * (2 * DINNER) + DINNER + d];
  float s = z / (1.f + __expf(-z));
  g[idx] = f2bf(y2[idx] * s);
}

extern "C" void kernel_launch(void* const* d_in, const int* in_sizes, int n_in,
                              void* d_out, int out_size, void* d_ws, size_t ws_size,
                              hipStream_t stream) {
  const float* in_x      = (const float*)d_in[0];
  const float* norm_w    = (const float*)d_in[1];
  const float* in_proj_w = (const float*)d_in[2];
  const float* conv_f_w  = (const float*)d_in[3];
  const float* conv_f_b  = (const float*)d_in[4];
  const float* conv_b_w  = (const float*)d_in[5];
  const float* conv_b_b  = (const float*)d_in[6];
  const float* xproj_f_w = (const float*)d_in[7];
  const float* xproj_b_w = (const float*)d_in[8];
  const float* dt_f_w    = (const float*)d_in[9];
  const float* dt_f_b    = (const float*)d_in[10];
  const float* dt_b_w    = (const float*)d_in[11];
  const float* dt_b_b    = (const float*)d_in[12];
  const float* A_log_f   = (const float*)d_in[13];
  const float* D_f       = (const float*)d_in[14];
  const float* A_log_b   = (const float*)d_in[15];
  const float* D_b       = (const float*)d_in[16];
  const float* out_w     = (const float*)d_in[17];
  const float* token_wA  = (const float*)d_in[18];
  const float* token_wV  = (const float*)d_in[19];
  const float* pro_w     = (const float*)d_in[20];
  const float* pro_b     = (const float*)d_in[21];

  // ---- workspace carve (fp32 units) ----
  float* ws = (float*)d_ws;
  float* xbuf = ws; ws += LSEQ * DMODEL;
  float* xz   = ws; ws += LSEQ * 2 * DINNER;
  float* xf   = ws; ws += LSEQ * DINNER;
  float* xb   = ws; ws += LSEQ * DINNER;
  float* dbcf = ws; ws += LSEQ * DBC;
  float* dbcb = ws; ws += LSEQ * DBC;
  float* delf = ws; ws += LSEQ * DINNER;   // alias: dbc partials pre-delta; Smat post-scan
  float* delb = ws; ws += LSEQ * DINNER;   // alias: Smat_bf post-scan
  float* y2   = ws; ws += LSEQ * DINNER;
  u16* xn_bf   = (u16*)ws; ws += (LSEQ * DMODEL) / 2;
  u16* ycat_bf = (u16*)ws; ws += LSEQ * DINNER;
  u16* ypro_bf = (u16*)ws; ws += (LSEQ * DINNER) / 2;
  u16* Wb      = (u16*)ws;
  u16* in_w_bf = Wb;
  u16* pw_bf   = in_w_bf + 3072 * 768;
  u16* wA_bf   = pw_bf + 1536 * 3072;
  u16* wVT_bf  = wA_bf + 1024 * 1536;
  u16* ow_bf   = wVT_bf + 1536 * 1536;

  // aliases (verified live ranges)
  float* dbc_part = delf;       // [16][1024][80] = 1.31M floats; dead before delta GEMM
  float* Smat    = delf;        // written after scans consume delf
  u16*   Smat_bf = (u16*)delb;
  u16*   vv_bf   = (u16*)xf;    // xf dead after scan-f
  u16*   vvT_bf  = (u16*)xb;    // xb dead after scan-b
  u16*   g_bf    = ypro_bf;     // ypro last read by vv gemm

  hipMemcpyAsync(xbuf, in_x, sizeof(float) * LSEQ * DMODEL,
                 hipMemcpyDeviceToDevice, stream);

  dim3 blk(256);
  for (int layer = 0; layer < NLAYER; layer++) {
    const float* nw  = norm_w    + (size_t)layer * DMODEL;
    const float* iw  = in_proj_w + (size_t)layer * 2 * DINNER * DMODEL;
    const float* cfw = conv_f_w  + (size_t)layer * DINNER * KCONV;
    const float* cfb = conv_f_b  + (size_t)layer * DINNER;
    const float* cbw = conv_b_w  + (size_t)layer * DINNER * KCONV;
    const float* cbb = conv_b_b  + (size_t)layer * DINNER;
    const float* xfw = xproj_f_w + (size_t)layer * DBC * DINNER;
    const float* xbw = xproj_b_w + (size_t)layer * DBC * DINNER;
    const float* dfw = dt_f_w    + (size_t)layer * DINNER * DRANK;
    const float* dfb = dt_f_b    + (size_t)layer * DINNER;
    const float* dbw = dt_b_w    + (size_t)layer * DINNER * DRANK;
    const float* dbb = dt_b_b    + (size_t)layer * DINNER;
    const float* Af  = A_log_f   + (size_t)layer * DINNER * DSTATE;
    const float* Df  = D_f       + (size_t)layer * DINNER;
    const float* Ab  = A_log_b   + (size_t)layer * DINNER * DSTATE;
    const float* Db  = D_b       + (size_t)layer * DINNER;
    const float* ow  = out_w     + (size_t)layer * DMODEL * DINNER;
    const float* wA  = token_wA  + (size_t)layer * LSEQ * DINNER;
    const float* wV  = token_wV  + (size_t)layer * DINNER * DINNER;
    const float* pw  = pro_w     + (size_t)layer * DINNER * 2 * DINNER;
    const float* pb  = pro_b     + (size_t)layer * DINNER;

    // weight conversions for this layer
    cvt_k<<<(3072 * 768 / 4 + 255) / 256, blk, 0, stream>>>(iw, in_w_bf, 3072 * 768 / 4);
    cvt_k<<<(1536 * 3072 / 4 + 255) / 256, blk, 0, stream>>>(pw, pw_bf, 1536 * 3072 / 4);
    cvt_k<<<(1024 * 1536 / 4 + 255) / 256, blk, 0, stream>>>(wA, wA_bf, 1024 * 1536 / 4);
    cvt_k<<<(768 * 1536 / 4 + 255) / 256, blk, 0, stream>>>(ow, ow_bf, 768 * 1536 / 4);
    transcvt_k<<<dim3(1536 / 32, 1536 / 32), blk, 0, stream>>>(wV, wVT_bf, 1536, 1536);

    rmsnorm_k<<<LSEQ, blk, 0, stream>>>(xbuf, nw, xn_bf);

    // xz = xn @ in_w^T   [1024,3072] k=768
    mgemm_k<0><<<dim3(3072 / 128, LSEQ / 128), blk, 0, stream>>>(
        xn_bf, DMODEL, in_w_bf, DMODEL, xz, 2 * DINNER, DMODEL, nullptr, nullptr, 0);

    conv_silu_k<<<dim3((LSEQ * DINNER) / 256, 2), blk, 0, stream>>>(
        xz, cfw, cfb, cbw, cbb, xf, xb);

    // dbc = x @ xproj^T  [1024,80] k=1536 (fp32, K-split thin GEMM)
    thin_gemm_k<<<dim3(LSEQ / TG_R, TG_KS), blk, 0, stream>>>(xf, xfw, dbc_part);
    reduce_dbc_k<<<(LSEQ * DBC) / 256, blk, 0, stream>>>(dbc_part, dbcf);
    thin_gemm_k<<<dim3(LSEQ / TG_R, TG_KS), blk, 0, stream>>>(xb, xbw, dbc_part);
    reduce_dbc_k<<<(LSEQ * DBC) / 256, blk, 0, stream>>>(dbc_part, dbcb);

    // delta = softplus(dlt @ dt_w^T + dt_b)  [1024,1536] k=48 (fp32)
    gemm_k<3><<<dim3(DINNER / BN, LSEQ / BM), blk, 0, stream>>>(
        dbcf, DBC, dfw, DRANK, delf, DINNER, LSEQ, DINNER, DRANK, dfb);
    gemm_k<3><<<dim3(DINNER / BN, LSEQ / BM), blk, 0, stream>>>(
        dbcb, DBC, dbw, DRANK, delb, DINNER, LSEQ, DINNER, DRANK, dbb);

    scan_k<<<DINNER / SCPB, blk, 0, stream>>>(xf, delf, dbcf, Af, Df, ycat_bf, 0);
    scan_k<<<DINNER / SCPB, blk, 0, stream>>>(xb, delb, dbcb, Ab, Db, ycat_bf, DINNER);

    // ypro = ycat @ pro_w^T + pro_b   [1024,1536] k=3072 -> bf16
    mgemm_k<9><<<dim3(DINNER / 128, LSEQ / 128), blk, 0, stream>>>(
        ycat_bf, 2 * DINNER, pw_bf, 2 * DINNER, ypro_bf, DINNER, 2 * DINNER,
        pb, nullptr, 0);

    // S = wA . ypro^T   [1024,1024] k=1536 -> fp32
    mgemm_k<0><<<dim3(LSEQ / 128, LSEQ / 128), blk, 0, stream>>>(
        wA_bf, DINNER, ypro_bf, DINNER, Smat, LSEQ, DINNER, nullptr, nullptr, 0);
    softmax_k<<<LSEQ, blk, 0, stream>>>(Smat, Smat_bf);

    // vv = ypro @ wV    [1024,1536] k=1536 -> bf16 (B = wV^T)
    mgemm_k<8><<<dim3(DINNER / 128, LSEQ / 128), blk, 0, stream>>>(
        ypro_bf, DINNER, wVT_bf, DINNER, vv_bf, DINNER, DINNER, nullptr, nullptr, 0);

    // vvT[e][l] = vv[l][e]
    transpose16_k<<<dim3(DINNER / 32, LSEQ / 32), blk, 0, stream>>>(
        vv_bf, vvT_bf, LSEQ, DINNER);

    // y2 = att @ vv     [1024,1536] k=1024 -> fp32 (B = vv^T)
    mgemm_k<0><<<dim3(DINNER / 128, LSEQ / 128), blk, 0, stream>>>(
        Smat_bf, LSEQ, vvT_bf, LSEQ, y2, DINNER, LSEQ, nullptr, nullptr, 0);

    silumul_k<<<(LSEQ * DINNER) / 256, blk, 0, stream>>>(y2, xz, g_bf);

    // x_next = x + g @ out_w^T   [1024,768] k=1536
    float* target = (layer == NLAYER - 1) ? (float*)d_out : xbuf;
    mgemm_k<4><<<dim3(DMODEL / 128, LSEQ / 128), blk, 0, stream>>>(
        g_bf, DINNER, ow_bf, DINNER, target, DMODEL, DINNER,
        nullptr, xbuf, DMODEL);
  }
}

// Round 7
// 523.552 us; speedup vs baseline: 1.4612x; 1.4612x over previous
//
#include <hip/hip_runtime.h>
#include <hip/hip_bf16.h>
#include <math.h>
#include <stdint.h>

#define LSEQ 1024
#define DMODEL 768
#define DINNER 1536
#define DSTATE 16
#define DRANK 48
#define KCONV 4
#define NLAYER 2
#define DBC 80  // DRANK + 2*DSTATE

typedef unsigned short u16;
typedef __attribute__((ext_vector_type(8))) __bf16 bf16x8;
typedef __attribute__((ext_vector_type(4))) float f32x4;
typedef __attribute__((ext_vector_type(4))) unsigned short us4;

__device__ __forceinline__ u16 f2bf(float f) {
  union { float f; unsigned u; } v; v.f = f;
  unsigned r = v.u + 0x7fffu + ((v.u >> 16) & 1u);  // RNE
  return (u16)(r >> 16);
}

// CK-style addrspace casts for global_load_lds (direct HBM->LDS DMA, 16B/lane)
__device__ __forceinline__ void gload16(const void* g, void* l) {
  auto gp = reinterpret_cast<const __attribute__((address_space(1))) uint32_t*>(
      reinterpret_cast<uintptr_t>(g));
  auto lp = reinterpret_cast<__attribute__((address_space(3))) uint32_t*>(
      reinterpret_cast<uintptr_t>(l));
  __builtin_amdgcn_global_load_lds(gp, lp, 16, 0, 0);
}

// ---------------- fp32 -> bf16 flat convert ----------------
__global__ __launch_bounds__(256) void cvt_k(const float* __restrict__ in,
                                             u16* __restrict__ out, int n4) {
  int i = blockIdx.x * 256 + threadIdx.x;
  if (i >= n4) return;
  float4 v = ((const float4*)in)[i];
  us4 o; o[0] = f2bf(v.x); o[1] = f2bf(v.y); o[2] = f2bf(v.z); o[3] = f2bf(v.w);
  ((us4*)out)[i] = o;
}

// ---------------- fp32 -> bf16 transpose-convert ----------------
__global__ __launch_bounds__(256) void transcvt_k(const float* __restrict__ in,
                                                  u16* __restrict__ out,
                                                  int R, int C) {
  __shared__ float t[32][33];
  int c0 = blockIdx.x * 32, r0 = blockIdx.y * 32;
  int tx = threadIdx.x & 31, ty = threadIdx.x >> 5;
  for (int i = ty; i < 32; i += 8) t[i][tx] = in[(size_t)(r0 + i) * C + c0 + tx];
  __syncthreads();
  for (int i = ty; i < 32; i += 8)
    out[(size_t)(c0 + i) * R + r0 + tx] = f2bf(t[tx][i]);
}

// ---------------- bf16 -> bf16 transpose ----------------
__global__ __launch_bounds__(256) void transpose16_k(const u16* __restrict__ in,
                                                     u16* __restrict__ out,
                                                     int R, int C) {
  __shared__ u16 t[32][34];
  int c0 = blockIdx.x * 32, r0 = blockIdx.y * 32;
  int tx = threadIdx.x & 31, ty = threadIdx.x >> 5;
  for (int i = ty; i < 32; i += 8) t[i][tx] = in[(size_t)(r0 + i) * C + c0 + tx];
  __syncthreads();
  for (int i = ty; i < 32; i += 8)
    out[(size_t)(c0 + i) * R + r0 + tx] = t[tx][i];
}

// ---------------- rmsnorm (bf16 out) ----------------
__global__ __launch_bounds__(256) void rmsnorm_k(const float* __restrict__ x,
                                                 const float* __restrict__ w,
                                                 u16* __restrict__ xn) {
  int row = blockIdx.x;
  int tid = threadIdx.x;
  const float* xr = x + (size_t)row * DMODEL;
  float ss = 0.f;
  for (int j = tid; j < DMODEL; j += 256) { float v = xr[j]; ss += v * v; }
  __shared__ float red[256];
  red[tid] = ss; __syncthreads();
  for (int s = 128; s > 0; s >>= 1) { if (tid < s) red[tid] += red[tid + s]; __syncthreads(); }
  float scale = rsqrtf(red[0] / (float)DMODEL + 1e-5f);
  u16* outr = xn + (size_t)row * DMODEL;
  for (int j = tid; j < DMODEL; j += 256) outr[j] = f2bf(xr[j] * scale * w[j]);
}

// ---------------- MFMA bf16 GEMM: 64x64 tile, BK=64, occupancy-first --------
// C[m,n] = sum_k A[m,k]*B[n,k]; A [M,K] bf16, B [N,K] bf16 (NT).
// 4 waves, each 32x32 (2x2 frags of 16x16x32). Double-buffered LDS (32 KB),
// __syncthreads per K-step (multi-block/CU TLP hides the drain, m114).
// LDS chunk-XOR swizzle (r&7): pre-swizzled global source (linear gload dest)
// + swizzled frag reads -> bank-optimal ds_read_b128 (rule #21).
// Bijective XCD swizzle on linear block id (all grids %8 == 0).
// EPI bit0: +bias[n]; bit2: +resid fp32; bit3: bf16 output.
template<int EPI>
__global__ __launch_bounds__(256) void mgemm_k(
    const u16* __restrict__ A, int lda,
    const u16* __restrict__ B, int ldb,
    void* __restrict__ Cv, int ldc, int K,
    const float* __restrict__ bias,
    const float* __restrict__ resid, int ldr)
{
  __shared__ u16 As[2][64 * 64];
  __shared__ u16 Bs[2][64 * 64];
  const int tid = threadIdx.x;
  const int lane = tid & 63;
  const int w = tid >> 6;

  // XCD-aware swizzle (nwg % 8 == 0 for every launch in this file)
  const int nbx = gridDim.x;
  int bid = blockIdx.y * nbx + blockIdx.x;
  const int nwg = nbx * gridDim.y;
  bid = (bid & 7) * (nwg >> 3) + (bid >> 3);
  const int bm = (bid / nbx) * 64;
  const int bn = (bid % nbx) * 64;

  // ---- staging map ----
  // gload g covers dest bytes g*1024 + lane*16 == row (g*8 + lane/8), chunk lane%8.
  // LDS chunk c of row r holds global chunk c ^ (r&7)  (involution).
  const int srow = lane >> 3;               // row-within-8 of this lane
  const int scs = (lane & 7) ^ srow;        // pre-swizzled source chunk
  const int gA = 2 * w;                     // this wave's gloads: gA, gA+1
  const u16* Asrc0 = A + (size_t)(bm + gA * 8 + srow) * lda + scs * 8;
  const u16* Asrc1 = Asrc0 + (size_t)8 * lda;
  const u16* Bsrc0 = B + (size_t)(bn + gA * 8 + srow) * ldb + scs * 8;
  const u16* Bsrc1 = Bsrc0 + (size_t)8 * ldb;
  const int d0 = gA * 512;                  // u16 dest offsets (wave-uniform)
  const int d1 = d0 + 512;

  // ---- fragment read offsets (swizzled) ----
  const int fr = lane & 15;
  const int fs = lane >> 4;                 // k sub-slot / acc row group
  const int wm = (w >> 1) * 32;
  const int wn = (w & 1) * 32;
  int aoff[2][2], boff[2][2];               // [frag][k-half]
#pragma unroll
  for (int i = 0; i < 2; i++)
#pragma unroll
    for (int h = 0; h < 2; h++) {
      const int g = h * 4 + fs;
      aoff[i][h] = (wm + i * 16 + fr) * 64 + (g ^ (fr & 7)) * 8;
      boff[i][h] = (wn + i * 16 + fr) * 64 + (g ^ (fr & 7)) * 8;
    }

  f32x4 acc[2][2];
#pragma unroll
  for (int i = 0; i < 2; i++)
#pragma unroll
    for (int j = 0; j < 2; j++) acc[i][j] = (f32x4){0.f, 0.f, 0.f, 0.f};

#define STAGE(buf, k0) do { \
    gload16(Asrc0 + (k0), &As[buf][d0]); \
    gload16(Asrc1 + (k0), &As[buf][d1]); \
    gload16(Bsrc0 + (k0), &Bs[buf][d0]); \
    gload16(Bsrc1 + (k0), &Bs[buf][d1]); \
  } while (0)

  const int nk = K >> 6;   // all K multiples of 64
  STAGE(0, 0);

  for (int t = 0; t < nk; t++) {
    const int buf = t & 1;
    __syncthreads();                       // drains vmcnt: buf landed, buf^1 free
    if (t + 1 < nk) STAGE(buf ^ 1, (t + 1) << 6);
    const u16* As_ = As[buf];
    const u16* Bs_ = Bs[buf];
#pragma unroll
    for (int h = 0; h < 2; h++) {
      bf16x8 a0 = *reinterpret_cast<const bf16x8*>(As_ + aoff[0][h]);
      bf16x8 a1 = *reinterpret_cast<const bf16x8*>(As_ + aoff[1][h]);
      bf16x8 b0 = *reinterpret_cast<const bf16x8*>(Bs_ + boff[0][h]);
      bf16x8 b1 = *reinterpret_cast<const bf16x8*>(Bs_ + boff[1][h]);
      acc[0][0] = __builtin_amdgcn_mfma_f32_16x16x32_bf16(a0, b0, acc[0][0], 0, 0, 0);
      acc[0][1] = __builtin_amdgcn_mfma_f32_16x16x32_bf16(a0, b1, acc[0][1], 0, 0, 0);
      acc[1][0] = __builtin_amdgcn_mfma_f32_16x16x32_bf16(a1, b0, acc[1][0], 0, 0, 0);
      acc[1][1] = __builtin_amdgcn_mfma_f32_16x16x32_bf16(a1, b1, acc[1][1], 0, 0, 0);
    }
  }
#undef STAGE

#pragma unroll
  for (int i = 0; i < 2; i++) {
#pragma unroll
    for (int j = 0; j < 2; j++) {
      const int col = bn + wn + j * 16 + fr;
      const int row0 = bm + wm + i * 16 + fs * 4;
      float bv = (EPI & 1) ? bias[col] : 0.f;
#pragma unroll
      for (int r = 0; r < 4; r++) {
        float v = acc[i][j][r] + bv;
        if (EPI & 4) v += resid[(size_t)(row0 + r) * ldr + col];
        if (EPI & 8) ((u16*)Cv)[(size_t)(row0 + r) * ldc + col] = f2bf(v);
        else         ((float*)Cv)[(size_t)(row0 + r) * ldc + col] = v;
      }
    }
  }
}

// ---------------- thin dbc GEMM (f+b merged): partial[dir][ks][1024][80] -----
#define TG_R 16
#define TG_KC 96
#define TG_KS 16

__global__ __launch_bounds__(256) void thin_gemm_k(
    const float* __restrict__ Af_, const float* __restrict__ Ab_,  // [1024][1536]
    const float* __restrict__ Bf_, const float* __restrict__ Bb_,  // [80][1536]
    float* __restrict__ partial)   // [2][TG_KS][1024][80]
{
  __shared__ float As[TG_R][100];
  __shared__ float Bs[80][100];
  const float* A = blockIdx.z ? Ab_ : Af_;
  const float* B = blockIdx.z ? Bb_ : Bf_;
  float* part = partial + (size_t)blockIdx.z * TG_KS * LSEQ * DBC;
  const int tid = threadIdx.x;
  const int m0 = blockIdx.x * TG_R;
  const int ks = blockIdx.y;
  const int k0 = ks * TG_KC;

  for (int i = tid; i < 384; i += 256) {   // A tile: 16 x 96 = 384 float4
    int r = i / 24, q = i % 24;
    *(float4*)&As[r][q * 4] = *(const float4*)(A + (size_t)(m0 + r) * DINNER + k0 + q * 4);
  }
  for (int i = tid; i < 1920; i += 256) {  // B tile: 80 x 96 = 1920 float4
    int r = i / 24, q = i % 24;
    *(float4*)&Bs[r][q * 4] = *(const float4*)(B + (size_t)r * DINNER + k0 + q * 4);
  }
  __syncthreads();

  const int r = tid >> 4;
  const int c0 = (tid & 15) * 5;
  float acc[5] = {};
  for (int k = 0; k < TG_KC; k++) {
    float a = As[r][k];
#pragma unroll
    for (int j = 0; j < 5; j++) acc[j] += a * Bs[c0 + j][k];
  }
  float* out = part + ((size_t)ks * LSEQ + m0 + r) * DBC + c0;
#pragma unroll
  for (int j = 0; j < 5; j++) out[j] = acc[j];
}

__global__ __launch_bounds__(256) void reduce_dbc_k(const float* __restrict__ partial,
                                                    float* __restrict__ outf,
                                                    float* __restrict__ outb) {
  int i = blockIdx.x * 256 + threadIdx.x;  // LSEQ*DBC = 81920
  const float* part = partial + (size_t)blockIdx.y * TG_KS * LSEQ * DBC;
  float s = 0.f;
#pragma unroll
  for (int ks = 0; ks < TG_KS; ks++) s += part[(size_t)ks * (LSEQ * DBC) + i];
  (blockIdx.y ? outb : outf)[i] = s;
}

// ---------------- delta = softplus(dlt @ dt_w^T + dt_b), f+b merged ----------
#define BM 64
#define BN 64
#define BK 16

__global__ __launch_bounds__(256) void delta_gemm_k(
    const float* __restrict__ A0, const float* __restrict__ A1,  // dbc [1024][80]
    const float* __restrict__ B0, const float* __restrict__ B1,  // dt_w [1536][48]
    const float* __restrict__ b0, const float* __restrict__ b1,
    float* __restrict__ C0, float* __restrict__ C1)
{
  __shared__ float Asf[BK][BM];
  __shared__ float Bsf[BK][BN + 4];
  const float* A = blockIdx.z ? A1 : A0;
  const float* B = blockIdx.z ? B1 : B0;
  const float* bias = blockIdx.z ? b1 : b0;
  float* C = blockIdx.z ? C1 : C0;
  const int tid = threadIdx.x;
  const int bm = blockIdx.y * BM;
  const int bn = blockIdx.x * BN;
  const int ar = tid >> 2;
  const int ak = (tid & 3) << 2;
  const int ty = tid >> 4, tx = tid & 15;
  float acc[4][4] = {};

  for (int k0 = 0; k0 < DRANK; k0 += BK) {
    float4 av = *(const float4*)(A + (size_t)(bm + ar) * DBC + k0 + ak);
    float4 bv = *(const float4*)(B + (size_t)(bn + ar) * DRANK + k0 + ak);
    __syncthreads();
    Asf[ak + 0][ar] = av.x; Asf[ak + 1][ar] = av.y;
    Asf[ak + 2][ar] = av.z; Asf[ak + 3][ar] = av.w;
    Bsf[ak + 0][ar] = bv.x; Bsf[ak + 1][ar] = bv.y;
    Bsf[ak + 2][ar] = bv.z; Bsf[ak + 3][ar] = bv.w;
    __syncthreads();
#pragma unroll
    for (int kk = 0; kk < BK; kk++) {
      float4 a4 = *(const float4*)&Asf[kk][ty * 4];
      float4 b4 = *(const float4*)&Bsf[kk][tx * 4];
      float a[4] = {a4.x, a4.y, a4.z, a4.w};
      float b[4] = {b4.x, b4.y, b4.z, b4.w};
#pragma unroll
      for (int i = 0; i < 4; i++)
#pragma unroll
        for (int j = 0; j < 4; j++)
          acc[i][j] += a[i] * b[j];
    }
  }

#pragma unroll
  for (int i = 0; i < 4; i++) {
    int row = bm + ty * 4 + i;
#pragma unroll
    for (int j = 0; j < 4; j++) {
      int col = bn + tx * 4 + j;
      float v = acc[i][j] + bias[col];
      v = (v > 20.f) ? v : log1pf(__expf(v));
      C[(size_t)row * DINNER + col] = v;
    }
  }
}

// ---------------- causal depthwise conv + silu (both directions) -------------
__global__ __launch_bounds__(256) void conv_silu_k(
    const float* __restrict__ xz,
    const float* __restrict__ wf, const float* __restrict__ bf,
    const float* __restrict__ wb, const float* __restrict__ bb,
    float* __restrict__ xf, float* __restrict__ xb)
{
  int idx = blockIdx.x * 256 + threadIdx.x;
  int dir = blockIdx.y;
  if (idx >= LSEQ * DINNER) return;
  int l = idx / DINNER, c = idx % DINNER;
  const float* w = (dir ? wb : wf) + c * KCONV;
  float acc = (dir ? bb : bf)[c];
#pragma unroll
  for (int k = 0; k < KCONV; k++) {
    int ls = l - (KCONV - 1) + k;
    if (ls >= 0) {
      int lsrc = dir ? (LSEQ - 1 - ls) : ls;
      acc += w[k] * xz[(size_t)lsrc * (2 * DINNER) + c];
    }
  }
  float sv = acc / (1.f + __expf(-acc));
  (dir ? xb : xf)[idx] = sv;
}

// ---------------- chunked selective scan, f+b merged: 64 chunks x 4 ch -------
#define SCH 64
#define SCPB 4
__global__ __launch_bounds__(256) void scan_k(
    const float* __restrict__ xcf, const float* __restrict__ xcb,
    const float* __restrict__ dltf, const float* __restrict__ dltb,
    const float* __restrict__ dbcf, const float* __restrict__ dbcb,
    const float* __restrict__ Af, const float* __restrict__ Ab,
    const float* __restrict__ Df, const float* __restrict__ Db,
    u16* __restrict__ ycat)
{
  __shared__ float sP[SCH * SCPB * DSTATE];
  __shared__ float sQ[SCH * SCPB * DSTATE];
  const int dir = blockIdx.y;
  const float* xc    = dir ? xcb : xcf;
  const float* delta = dir ? dltb : dltf;
  const float* dbc   = dir ? dbcb : dbcf;
  const float* A_log = dir ? Ab : Af;
  const float* Dvec  = dir ? Db : Df;
  const int col_off  = dir ? DINNER : 0;

  const int tid = threadIdx.x;
  const int c = tid >> 2;
  const int dl = tid & 3;
  const int d = blockIdx.x * SCPB + dl;
  const int CH = LSEQ / SCH;

  float Aa[DSTATE];
#pragma unroll
  for (int s = 0; s < DSTATE; s++) Aa[s] = -__expf(A_log[(size_t)d * DSTATE + s]);

  float aP[DSTATE], q[DSTATE];
#pragma unroll
  for (int s = 0; s < DSTATE; s++) { aP[s] = 1.f; q[s] = 0.f; }
  const int l0 = c * CH;
  for (int i = 0; i < CH; i++) {
    int l = l0 + i;
    float dt = delta[(size_t)l * DINNER + d];
    float dx = dt * xc[(size_t)l * DINNER + d];
    const float* bm = dbc + (size_t)l * DBC + DRANK;
#pragma unroll
    for (int s = 0; s < DSTATE; s++) {
      float a = __expf(dt * Aa[s]);
      q[s] = a * q[s] + dx * bm[s];
      aP[s] *= a;
    }
  }
#pragma unroll
  for (int s = 0; s < DSTATE; s++) {
    sP[(c * SCPB + dl) * DSTATE + s] = aP[s];
    sQ[(c * SCPB + dl) * DSTATE + s] = q[s];
  }
  __syncthreads();

  if (tid < SCPB * DSTATE) {
    const int d2 = tid >> 4, s2 = tid & 15;
    float h = 0.f;
    for (int cc = 0; cc < SCH; cc++) {
      int idx = (cc * SCPB + d2) * DSTATE + s2;
      float a = sP[idx], qq = sQ[idx];
      sP[idx] = h;
      h = a * h + qq;
    }
  }
  __syncthreads();

  float hs[DSTATE];
#pragma unroll
  for (int s = 0; s < DSTATE; s++) hs[s] = sP[(c * SCPB + dl) * DSTATE + s];
  const float Dd = Dvec[d];
  for (int i = 0; i < CH; i++) {
    int l = l0 + i;
    float dt = delta[(size_t)l * DINNER + d];
    float xv = xc[(size_t)l * DINNER + d];
    float dx = dt * xv;
    const float* bm = dbc + (size_t)l * DBC + DRANK;
    const float* cm = bm + DSTATE;
    float y = 0.f;
#pragma unroll
    for (int s = 0; s < DSTATE; s++) {
      float a = __expf(dt * Aa[s]);
      hs[s] = a * hs[s] + dx * bm[s];
      y += hs[s] * cm[s];
    }
    ycat[(size_t)l * (2 * DINNER) + col_off + d] = f2bf(y + Dd * xv);
  }
}

// ---------------- row softmax (fp32 in, bf16 out) ----------------
__global__ __launch_bounds__(256) void softmax_k(const float* __restrict__ S,
                                                 u16* __restrict__ P) {
  int row = blockIdx.x, tid = threadIdx.x;
  __shared__ float buf[LSEQ];
  __shared__ float red[256];
  const float* r = S + (size_t)row * LSEQ;
  float m = -1e30f;
  for (int j = tid; j < LSEQ; j += 256) { float v = r[j]; buf[j] = v; m = fmaxf(m, v); }
  red[tid] = m; __syncthreads();
  for (int s = 128; s > 0; s >>= 1) { if (tid < s) red[tid] = fmaxf(red[tid], red[tid + s]); __syncthreads(); }
  m = red[0];
  __syncthreads();
  float sum = 0.f;
  for (int j = tid; j < LSEQ; j += 256) { float e = __expf(buf[j] - m); buf[j] = e; sum += e; }
  red[tid] = sum; __syncthreads();
  for (int s = 128; s > 0; s >>= 1) { if (tid < s) red[tid] += red[tid + s]; __syncthreads(); }
  float inv = 1.f / red[0];
  u16* pr = P + (size_t)row * LSEQ;
  for (int j = tid; j < LSEQ; j += 256) pr[j] = f2bf(buf[j] * inv);
}

// ---------------- g = y2 * silu(z) (bf16 out) ----------------
__global__ __launch_bounds__(256) void silumul_k(const float* __restrict__ y2,
                                                 const float* __restrict__ xz,
                                                 u16* __restrict__ g) {
  int idx = blockIdx.x * 256 + threadIdx.x;
  if (idx >= LSEQ * DINNER) return;
  int l = idx / DINNER, d = idx % DINNER;
  float z = xz[(size_t)l * (2 * DINNER) + DINNER + d];
  float s = z / (1.f + __expf(-z));
  g[idx] = f2bf(y2[idx] * s);
}

extern "C" void kernel_launch(void* const* d_in, const int* in_sizes, int n_in,
                              void* d_out, int out_size, void* d_ws, size_t ws_size,
                              hipStream_t stream) {
  const float* in_x      = (const float*)d_in[0];
  const float* norm_w    = (const float*)d_in[1];
  const float* in_proj_w = (const float*)d_in[2];
  const float* conv_f_w  = (const float*)d_in[3];
  const float* conv_f_b  = (const float*)d_in[4];
  const float* conv_b_w  = (const float*)d_in[5];
  const float* conv_b_b  = (const float*)d_in[6];
  const float* xproj_f_w = (const float*)d_in[7];
  const float* xproj_b_w = (const float*)d_in[8];
  const float* dt_f_w    = (const float*)d_in[9];
  const float* dt_f_b    = (const float*)d_in[10];
  const float* dt_b_w    = (const float*)d_in[11];
  const float* dt_b_b    = (const float*)d_in[12];
  const float* A_log_f   = (const float*)d_in[13];
  const float* D_f       = (const float*)d_in[14];
  const float* A_log_b   = (const float*)d_in[15];
  const float* D_b       = (const float*)d_in[16];
  const float* out_w     = (const float*)d_in[17];
  const float* token_wA  = (const float*)d_in[18];
  const float* token_wV  = (const float*)d_in[19];
  const float* pro_w     = (const float*)d_in[20];
  const float* pro_b     = (const float*)d_in[21];

  // ---- workspace carve (fp32 units) ----
  float* ws = (float*)d_ws;
  float* xbuf = ws; ws += LSEQ * DMODEL;
  float* xz   = ws; ws += LSEQ * 2 * DINNER;
  float* xf   = ws; ws += LSEQ * DINNER;
  float* xb   = ws; ws += LSEQ * DINNER;
  float* dbcf = ws; ws += LSEQ * DBC;
  float* dbcb = ws; ws += LSEQ * DBC;
  float* delf = ws; ws += LSEQ * DINNER;   // +delb: dbc partials pre-delta; Smat post-scan
  float* delb = ws; ws += LSEQ * DINNER;
  float* y2   = ws; ws += LSEQ * DINNER;
  u16* xn_bf   = (u16*)ws; ws += (LSEQ * DMODEL) / 2;
  u16* ycat_bf = (u16*)ws; ws += LSEQ * DINNER;
  u16* ypro_bf = (u16*)ws; ws += (LSEQ * DINNER) / 2;
  u16* Wb      = (u16*)ws;
  u16* in_w_bf = Wb;
  u16* pw_bf   = in_w_bf + 3072 * 768;
  u16* wA_bf   = pw_bf + 1536 * 3072;
  u16* wVT_bf  = wA_bf + 1024 * 1536;
  u16* ow_bf   = wVT_bf + 1536 * 1536;

  // aliases (verified live ranges)
  float* dbc_part = delf;       // [2][16][1024][80] = 2.62M fl <= delf+delb (3.1M, contiguous)
  float* Smat    = delf;        // written after scans consume delf
  u16*   Smat_bf = (u16*)delb;
  u16*   vv_bf   = (u16*)xf;    // xf dead after scan
  u16*   vvT_bf  = (u16*)xb;    // xb dead after scan
  u16*   g_bf    = ypro_bf;     // ypro last read by vv gemm

  hipMemcpyAsync(xbuf, in_x, sizeof(float) * LSEQ * DMODEL,
                 hipMemcpyDeviceToDevice, stream);

  dim3 blk(256);
  for (int layer = 0; layer < NLAYER; layer++) {
    const float* nw  = norm_w    + (size_t)layer * DMODEL;
    const float* iw  = in_proj_w + (size_t)layer * 2 * DINNER * DMODEL;
    const float* cfw = conv_f_w  + (size_t)layer * DINNER * KCONV;
    const float* cfb = conv_f_b  + (size_t)layer * DINNER;
    const float* cbw = conv_b_w  + (size_t)layer * DINNER * KCONV;
    const float* cbb = conv_b_b  + (size_t)layer * DINNER;
    const float* xfw = xproj_f_w + (size_t)layer * DBC * DINNER;
    const float* xbw = xproj_b_w + (size_t)layer * DBC * DINNER;
    const float* dfw = dt_f_w    + (size_t)layer * DINNER * DRANK;
    const float* dfb = dt_f_b    + (size_t)layer * DINNER;
    const float* dbw = dt_b_w    + (size_t)layer * DINNER * DRANK;
    const float* dbb = dt_b_b    + (size_t)layer * DINNER;
    const float* Af  = A_log_f   + (size_t)layer * DINNER * DSTATE;
    const float* Df  = D_f       + (size_t)layer * DINNER;
    const float* Ab  = A_log_b   + (size_t)layer * DINNER * DSTATE;
    const float* Db  = D_b       + (size_t)layer * DINNER;
    const float* ow  = out_w     + (size_t)layer * DMODEL * DINNER;
    const float* wA  = token_wA  + (size_t)layer * LSEQ * DINNER;
    const float* wV  = token_wV  + (size_t)layer * DINNER * DINNER;
    const float* pw  = pro_w     + (size_t)layer * DINNER * 2 * DINNER;
    const float* pb  = pro_b     + (size_t)layer * DINNER;

    // weight conversions for this layer
    cvt_k<<<(3072 * 768 / 4 + 255) / 256, blk, 0, stream>>>(iw, in_w_bf, 3072 * 768 / 4);
    cvt_k<<<(1536 * 3072 / 4 + 255) / 256, blk, 0, stream>>>(pw, pw_bf, 1536 * 3072 / 4);
    cvt_k<<<(1024 * 1536 / 4 + 255) / 256, blk, 0, stream>>>(wA, wA_bf, 1024 * 1536 / 4);
    cvt_k<<<(768 * 1536 / 4 + 255) / 256, blk, 0, stream>>>(ow, ow_bf, 768 * 1536 / 4);
    transcvt_k<<<dim3(1536 / 32, 1536 / 32), blk, 0, stream>>>(wV, wVT_bf, 1536, 1536);

    rmsnorm_k<<<LSEQ, blk, 0, stream>>>(xbuf, nw, xn_bf);

    // xz = xn @ in_w^T   [1024,3072] k=768   (grid 768)
    mgemm_k<0><<<dim3(3072 / 64, LSEQ / 64), blk, 0, stream>>>(
        xn_bf, DMODEL, in_w_bf, DMODEL, xz, 2 * DINNER, DMODEL, nullptr, nullptr, 0);

    conv_silu_k<<<dim3((LSEQ * DINNER) / 256, 2), blk, 0, stream>>>(
        xz, cfw, cfb, cbw, cbb, xf, xb);

    // dbc = x @ xproj^T  [1024,80] k=1536 (f+b merged K-split thin GEMM)
    thin_gemm_k<<<dim3(LSEQ / TG_R, TG_KS, 2), blk, 0, stream>>>(
        xf, xb, xfw, xbw, dbc_part);
    reduce_dbc_k<<<dim3((LSEQ * DBC) / 256, 2), blk, 0, stream>>>(
        dbc_part, dbcf, dbcb);

    // delta = softplus(dlt @ dt_w^T + dt_b)  [1024,1536] k=48 (f+b merged)
    delta_gemm_k<<<dim3(DINNER / BN, LSEQ / BM, 2), blk, 0, stream>>>(
        dbcf, dbcb, dfw, dbw, dfb, dbb, delf, delb);

    // selective scans (f+b merged)
    scan_k<<<dim3(DINNER / SCPB, 2), blk, 0, stream>>>(
        xf, xb, delf, delb, dbcf, dbcb, Af, Ab, Df, Db, ycat_bf);

    // ypro = ycat @ pro_w^T + pro_b   [1024,1536] k=3072 -> bf16  (grid 384)
    mgemm_k<9><<<dim3(DINNER / 64, LSEQ / 64), blk, 0, stream>>>(
        ycat_bf, 2 * DINNER, pw_bf, 2 * DINNER, ypro_bf, DINNER, 2 * DINNER,
        pb, nullptr, 0);

    // S = wA . ypro^T   [1024,1024] k=1536 -> fp32  (grid 256)
    mgemm_k<0><<<dim3(LSEQ / 64, LSEQ / 64), blk, 0, stream>>>(
        wA_bf, DINNER, ypro_bf, DINNER, Smat, LSEQ, DINNER, nullptr, nullptr, 0);
    softmax_k<<<LSEQ, blk, 0, stream>>>(Smat, Smat_bf);

    // vv = ypro @ wV    [1024,1536] k=1536 -> bf16 (B = wV^T)  (grid 384)
    mgemm_k<8><<<dim3(DINNER / 64, LSEQ / 64), blk, 0, stream>>>(
        ypro_bf, DINNER, wVT_bf, DINNER, vv_bf, DINNER, DINNER, nullptr, nullptr, 0);

    // vvT[e][l] = vv[l][e]
    transpose16_k<<<dim3(DINNER / 32, LSEQ / 32), blk, 0, stream>>>(
        vv_bf, vvT_bf, LSEQ, DINNER);

    // y2 = att @ vv     [1024,1536] k=1024 -> fp32 (B = vv^T)  (grid 384)
    mgemm_k<0><<<dim3(DINNER / 64, LSEQ / 64), blk, 0, stream>>>(
        Smat_bf, LSEQ, vvT_bf, LSEQ, y2, DINNER, LSEQ, nullptr, nullptr, 0);

    silumul_k<<<(LSEQ * DINNER) / 256, blk, 0, stream>>>(y2, xz, g_bf);

    // x_next = x + g @ out_w^T   [1024,768] k=1536  (grid 192)
    float* target = (layer == NLAYER - 1) ? (float*)d_out : xbuf;
    mgemm_k<4><<<dim3(DMODEL / 64, LSEQ / 64), blk, 0, stream>>>(
        g_bf, DINNER, ow_bf, DINNER, target, DMODEL, DINNER,
        nullptr, xbuf, DMODEL);
  }
}